// Round 11
// baseline (223.456 us; speedup 1.0000x reference)
//
#include <hip/hip_runtime.h>
#include <math.h>

typedef float  f32x4 __attribute__((ext_vector_type(4)));
typedef float  f32x2 __attribute__((ext_vector_type(2)));
typedef __bf16 bf16x8 __attribute__((ext_vector_type(8)));
typedef unsigned short u16x8 __attribute__((ext_vector_type(8)));
typedef unsigned short u16x4 __attribute__((ext_vector_type(4)));

#define DEVI __device__ __forceinline__

constexpr int Bc = 4, Tc = 2048, Cc = 1024, Hc = 16, HSc = 64;
constexpr int Mc  = Bc * Tc;    // 8192 rows
constexpr int N1c = 3 * Cc;     // 3072 qkv cols
constexpr int Kc  = Cc;         // 1024 reduce dim

DEVI unsigned short f2bf(float f) {            // RNE fp32 -> bf16
    unsigned u = __builtin_bit_cast(unsigned, f);
    u += 0x7FFFu + ((u >> 16) & 1u);
    return (unsigned short)(u >> 16);
}
DEVI float bf2f(unsigned short s) {
    unsigned u = ((unsigned)s) << 16;
    return __builtin_bit_cast(float, u);
}

typedef const __attribute__((address_space(1))) void* gbl_vp;
typedef __attribute__((address_space(3))) void* lds_vp;
DEVI void gload16(const unsigned short* g, unsigned short* l) {
    __builtin_amdgcn_global_load_lds((gbl_vp)g, (lds_vp)l, 16, 0, 0);
}

// ---------------------------------------------------------------------------
// Prep 0: RoPE table  tab[t][d] = (cos(t*theta_d), sin(t*theta_d)), d=0..31
// ---------------------------------------------------------------------------
__global__ void rope_tab_kernel(f32x2* __restrict__ tab)
{
    const int i = blockIdx.x * blockDim.x + threadIdx.x;   // 0 .. 2048*32
    const int t = i >> 5, d = i & 31;
    float theta = exp2f(-(float)d * 0.41524101186186f);    // 10000^(-d/32)
    float s, c;
    sincosf((float)t * theta, &s, &c);
    f32x2 v; v[0] = c; v[1] = s;
    tab[i] = v;
}

// ---------------------------------------------------------------------------
// Prep 1: fp32 -> bf16 elementwise (x). 8 elems/thread.
// ---------------------------------------------------------------------------
__global__ void cvt_kernel(const float* __restrict__ in,
                           unsigned short* __restrict__ out)
{
    const size_t i = ((size_t)blockIdx.x * blockDim.x + threadIdx.x) * 8;
    f32x4 a = *reinterpret_cast<const f32x4*>(in + i);
    f32x4 b = *reinterpret_cast<const f32x4*>(in + i + 4);
    u16x8 o;
    o[0] = f2bf(a[0]); o[1] = f2bf(a[1]); o[2] = f2bf(a[2]); o[3] = f2bf(a[3]);
    o[4] = f2bf(b[0]); o[5] = f2bf(b[1]); o[6] = f2bf(b[2]); o[7] = f2bf(b[3]);
    *reinterpret_cast<u16x8*>(out + i) = o;
}

// ---------------------------------------------------------------------------
// Prep 2: W [K][N] fp32 -> Wt [N][K] bf16 (transpose + convert), 64x64 tiles.
// ---------------------------------------------------------------------------
__global__ void wt_kernel(const float* __restrict__ W,
                          unsigned short* __restrict__ Wt, int N, int K)
{
    __shared__ unsigned short Ts[64][72];
    const int tid = threadIdx.x;
    const int n0 = blockIdx.x * 64, k0 = blockIdx.y * 64;

    #pragma unroll
    for (int i = 0; i < 4; ++i) {
        int kr = (tid >> 4) + i * 16, nc = (tid & 15) * 4;
        f32x4 v = *reinterpret_cast<const f32x4*>(W + (size_t)(k0 + kr) * N + n0 + nc);
        #pragma unroll
        for (int e = 0; e < 4; ++e) Ts[kr][nc + e] = f2bf(v[e]);
    }
    __syncthreads();
    #pragma unroll
    for (int i = 0; i < 2; ++i) {
        int s = tid * 2 + i;
        int n = s >> 3, k8 = (s & 7) * 8;
        u16x8 o;
        #pragma unroll
        for (int j = 0; j < 8; ++j) o[j] = Ts[k8 + j][n];
        *reinterpret_cast<u16x8*>(Wt + (size_t)(n0 + n) * K + k0 + k8) = o;
    }
}

// ---------------------------------------------------------------------------
// gemm8: 256x256 tile, BK=64, 512 thr = 8 waves (2M x 4N), 8-phase schedule.
// 2 K-tiles/iter in 2 LDS buffers (128 KB). One half-tile (128 rows) staged
// per phase via global_load_lds w=16 (pre-swizzled source, XOR ds_read).
// vmcnt(4) ONLY at phases 4 and 8 (retires current tile, keeps 2 half-tiles
// in flight). Each phase: {ds_reads || stage} -> barrier -> lgkmcnt(0) ->
// setprio(1) 16 MFMA setprio(0) -> barrier.
// Stage schedule (iter it, tiles E=2it buf0 / O=2it+1 buf1):
//   ph1:A0(O) ph2:A1(O) ph3:B0(E') ph4:B1(E') ph5:A0(E') ph6:A1(E')
//   ph7:B0(O') ph8:B1(O')    [E'=2it+2, O'=2it+3; region-liveness proven]
// Epilogue: fused table-RoPE + Q/K/Vt scatter (256 | 1024 -> tsel uniform).
// ---------------------------------------------------------------------------
__launch_bounds__(512, 2)
__global__ void gemm8_kernel(const unsigned short* __restrict__ A,
                             const unsigned short* __restrict__ Bt,
                             const float* __restrict__ bias,
                             const f32x2* __restrict__ rope_t,
                             unsigned short* __restrict__ q_out,
                             unsigned short* __restrict__ k_out,
                             unsigned short* __restrict__ v_out)
{
    __shared__ unsigned short As[2][256 * 64];   // 64 KB
    __shared__ unsigned short Bs[2][256 * 64];   // 64 KB

    const int tid = threadIdx.x, lane = tid & 63, wid = tid >> 6;
    const int wr = wid >> 2, wc = wid & 3;        // 2 x 4 waves
    const int lrow = lane & 15, lk = lane >> 4;

    const int cpx = gridDim.x >> 3;               // 384 -> 48
    const int wg  = (blockIdx.x & 7) * cpx + (blockIdx.x >> 3);
    const int m0 = (wg / 12) * 256, n0 = (wg % 12) * 256;

    // stage half h (rows h*128..h*128+127) of K-tile kt into buf (2 gloads/thr)
    auto stageA = [&](int buf, int kt, int h) {
        #pragma unroll
        for (int i = 0; i < 2; ++i) {
            const int sl  = i * 512 + wid * 64 + lane;        // 0..1023 slot
            const int row = h * 128 + (sl >> 3);
            const int gc  = (sl & 7) ^ (row & 7);
            gload16(A + (size_t)(m0 + row) * Kc + kt * 64 + gc * 8,
                    &As[buf][(h * 1024 + i * 512 + wid * 64) * 8]);
        }
    };
    auto stageB = [&](int buf, int kt, int h) {
        #pragma unroll
        for (int i = 0; i < 2; ++i) {
            const int sl  = i * 512 + wid * 64 + lane;
            const int row = h * 128 + (sl >> 3);
            const int gc  = (sl & 7) ^ (row & 7);
            gload16(Bt + (size_t)(n0 + row) * Kc + kt * 64 + gc * 8,
                    &Bs[buf][(h * 1024 + i * 512 + wid * 64) * 8]);
        }
    };

    f32x4  acc[8][4] = {};
    bf16x8 aR[4][2];          // current A quadrant (4 frags x 2 kk)
    bf16x8 bR[2][2][2];       // B [nh][frag][kk] — both halves live

    auto LDA = [&](int buf, int mh) {
        #pragma unroll
        for (int f = 0; f < 4; ++f) {
            const int ra = wr * 128 + (mh * 4 + f) * 16 + lrow;
            #pragma unroll
            for (int kk = 0; kk < 2; ++kk)
                aR[f][kk] = __builtin_bit_cast(bf16x8,
                    *reinterpret_cast<const u16x8*>(&As[buf][ra * 64 + (((kk * 4 + lk) ^ (ra & 7)) << 3)]));
        }
    };
    auto LDB = [&](int buf, int nh) {
        #pragma unroll
        for (int g = 0; g < 2; ++g) {
            const int rb = wc * 64 + (nh * 2 + g) * 16 + lrow;
            #pragma unroll
            for (int kk = 0; kk < 2; ++kk)
                bR[nh][g][kk] = __builtin_bit_cast(bf16x8,
                    *reinterpret_cast<const u16x8*>(&Bs[buf][rb * 64 + (((kk * 4 + lk) ^ (rb & 7)) << 3)]));
        }
    };
    auto MFMA16 = [&](int mh, int nh) {
        __builtin_amdgcn_s_setprio(1);
        #pragma unroll
        for (int f = 0; f < 4; ++f)
            #pragma unroll
            for (int g = 0; g < 2; ++g)
                #pragma unroll
                for (int kk = 0; kk < 2; ++kk)
                    acc[mh * 4 + f][nh * 2 + g] = __builtin_amdgcn_mfma_f32_16x16x32_bf16(
                        aR[f][kk], bR[nh][g][kk], acc[mh * 4 + f][nh * 2 + g], 0, 0, 0);
        __builtin_amdgcn_s_setprio(0);
    };
    auto MIDBAR = [&]() {
        __builtin_amdgcn_s_barrier();
        asm volatile("s_waitcnt lgkmcnt(0)" ::: "memory");
        __builtin_amdgcn_sched_barrier(0);
    };

    // ---- prologue: B0(0) B1(0) A0(0) A1(0) B0(1) B1(1); vmcnt(4); barrier
    stageB(0, 0, 0); stageB(0, 0, 1); stageA(0, 0, 0); stageA(0, 0, 1);
    stageB(1, 1, 0); stageB(1, 1, 1);
    asm volatile("s_waitcnt vmcnt(4)" ::: "memory");
    __builtin_amdgcn_s_barrier();

    for (int it = 0; it < 8; ++it) {
        const bool Ep = (2 * it + 2) < 16;        // E' exists
        const bool Op = (2 * it + 3) < 16;        // O' exists

        // ---- ph1: E m0n0; stage A0(O) -> buf1
        LDA(0, 0); LDB(0, 0);
        stageA(1, 2 * it + 1, 0);
        asm volatile("s_waitcnt lgkmcnt(8)" ::: "memory");
        MIDBAR(); MFMA16(0, 0);
        __builtin_amdgcn_s_barrier();

        // ---- ph2: E m0n1; stage A1(O) -> buf1
        LDB(0, 1);
        stageA(1, 2 * it + 1, 1);
        MIDBAR(); MFMA16(0, 1);
        __builtin_amdgcn_s_barrier();

        // ---- ph3: E m1n0; stage B0(E') -> buf0 (B freed after ph2)
        LDA(0, 1);
        if (Ep) stageB(0, 2 * it + 2, 0);
        MIDBAR(); MFMA16(1, 0);
        __builtin_amdgcn_s_barrier();

        // ---- ph4: E m1n1; stage B1(E'); tile-boundary wait
        if (Ep) stageB(0, 2 * it + 2, 1);
        MIDBAR(); MFMA16(1, 1);
        if (Ep) asm volatile("s_waitcnt vmcnt(4)" ::: "memory");
        else    asm volatile("s_waitcnt vmcnt(0)" ::: "memory");
        __builtin_amdgcn_s_barrier();             // O fully staged+visible

        // ---- ph5: O m0n0; stage A0(E') -> buf0 (A freed after ph3)
        LDA(1, 0); LDB(1, 0);
        if (Ep) stageA(0, 2 * it + 2, 0);
        asm volatile("s_waitcnt lgkmcnt(8)" ::: "memory");
        MIDBAR(); MFMA16(0, 0);
        __builtin_amdgcn_s_barrier();

        // ---- ph6: O m0n1; stage A1(E')
        LDB(1, 1);
        if (Ep) stageA(0, 2 * it + 2, 1);
        MIDBAR(); MFMA16(0, 1);
        __builtin_amdgcn_s_barrier();

        // ---- ph7: O m1n0; stage B0(O') -> buf1 (B freed after ph6)
        LDA(1, 1);
        if (Op) stageB(1, 2 * it + 3, 0);
        MIDBAR(); MFMA16(1, 0);
        __builtin_amdgcn_s_barrier();

        // ---- ph8: O m1n1; stage B1(O'); tile-boundary wait
        if (Op) stageB(1, 2 * it + 3, 1);
        MIDBAR(); MFMA16(1, 1);
        if (Op) asm volatile("s_waitcnt vmcnt(4)" ::: "memory");
        else    asm volatile("s_waitcnt vmcnt(0)" ::: "memory");
        __builtin_amdgcn_s_barrier();             // next E staged+visible
    }

    // ---- epilogue: bias + fused table-RoPE + scatter
    #pragma unroll
    for (int mt = 0; mt < 8; ++mt) {
        #pragma unroll
        for (int nt = 0; nt < 4; ++nt) {
            #pragma unroll
            for (int r = 0; r < 4; ++r) {
                int grow = m0 + wr * 128 + mt * 16 + lk * 4 + r;
                int gcol = n0 + wc * 64 + nt * 16 + lrow;
                float val = acc[mt][nt][r] + bias[gcol];
                int tsel = gcol >> 10;            // 0:q 1:k 2:v (block-uniform)
                int cc   = gcol & 1023;
                int h    = cc >> 6, hs = cc & 63;
                int bb   = grow >> 11, t = grow & (Tc - 1);
                int bh   = bb * Hc + h;
                if (tsel == 2) {
                    v_out[((size_t)bh * HSc + hs) * Tc + t] = f2bf(val);
                } else {
                    float partner = __shfl_xor(val, 1, 64);
                    const bool ev = !(lrow & 1);
                    float x1 = ev ? val : partner;
                    float x2 = ev ? partner : val;
                    int d = hs >> 1;
                    f32x2 cs = rope_t[t * 32 + d];
                    float o = ev ? (x1 * cs[0] - x2 * cs[1])
                                 : (x1 * cs[1] + x2 * cs[0]);
                    int hs_out = ev ? d : d + 32;
                    unsigned short* dst = (tsel == 0) ? q_out : k_out;
                    dst[((size_t)bh * Tc + t) * HSc + hs_out] = f2bf(o);
                }
            }
        }
    }
}

// ---------------------------------------------------------------------------
// Output-projection GEMM (R7/R10 proven 128^2, 4x4 frag loop, MODE 1).
// ---------------------------------------------------------------------------
__global__ void gemm1_kernel(const unsigned short* __restrict__ A,
                             const unsigned short* __restrict__ Bt,
                             const float* __restrict__ bias,
                             float* __restrict__ f_out)
{
    __shared__ unsigned short As[128 * 64];
    __shared__ unsigned short Bs[128 * 64];

    const int tid  = threadIdx.x;
    const int lane = tid & 63, wid = tid >> 6;
    const int wr = wid >> 1, wc = wid & 1;
    const int lrow = lane & 15, lk = lane >> 4;

    const int cpx = gridDim.x >> 3;
    const int wg  = (blockIdx.x & 7) * cpx + (blockIdx.x >> 3);
    constexpr int NBX = Cc / 128;
    const int m0 = (wg / NBX) * 128, n0 = (wg % NBX) * 128;

    f32x4 acc[4][4] = {};

    for (int kt = 0; kt < Kc / 64; ++kt) {
        const int k0 = kt * 64;
        #pragma unroll
        for (int i = 0; i < 4; ++i) {
            const int s   = ((i * 4 + wid) << 6) + lane;
            const int row = s >> 3;
            const int gc  = (s & 7) ^ (row & 7);
            gload16(A  + (size_t)(m0 + row) * Kc + k0 + gc * 8, &As[(i * 4 + wid) << 9]);
            gload16(Bt + (size_t)(n0 + row) * Kc + k0 + gc * 8, &Bs[(i * 4 + wid) << 9]);
        }
        __syncthreads();

        #pragma unroll
        for (int kk = 0; kk < 2; ++kk) {
            bf16x8 a[4], b[4];
            #pragma unroll
            for (int mt = 0; mt < 4; ++mt) {
                const int ra = wr * 64 + mt * 16 + lrow;
                a[mt] = __builtin_bit_cast(bf16x8,
                    *reinterpret_cast<const u16x8*>(&As[ra * 64 + (((kk * 4 + lk) ^ (ra & 7)) << 3)]));
            }
            #pragma unroll
            for (int nt = 0; nt < 4; ++nt) {
                const int rb = wc * 64 + nt * 16 + lrow;
                b[nt] = __builtin_bit_cast(bf16x8,
                    *reinterpret_cast<const u16x8*>(&Bs[rb * 64 + (((kk * 4 + lk) ^ (rb & 7)) << 3)]));
            }
            #pragma unroll
            for (int mt = 0; mt < 4; ++mt)
                #pragma unroll
                for (int nt = 0; nt < 4; ++nt)
                    acc[mt][nt] = __builtin_amdgcn_mfma_f32_16x16x32_bf16(a[mt], b[nt], acc[mt][nt], 0, 0, 0);
        }
        __syncthreads();
    }

    #pragma unroll
    for (int mt = 0; mt < 4; ++mt)
        #pragma unroll
        for (int nt = 0; nt < 4; ++nt)
            #pragma unroll
            for (int r = 0; r < 4; ++r) {
                int grow = m0 + wr * 64 + mt * 16 + lk * 4 + r;
                int gcol = n0 + wc * 64 + nt * 16 + lrow;
                f_out[(size_t)grow * Cc + gcol] = acc[mt][nt][r] + bias[gcol];
            }
}

// ---------------------------------------------------------------------------
// Causal flash attention v6 (R10 proven): wave = 32 q-rows, K/V frag reuse,
// dbuf + counted vmcnt(4), no running max, deferred row-sum, XCD-local LPT,
// sequential-f P buffer -> 3 blocks/CU.
// ---------------------------------------------------------------------------
__launch_bounds__(256, 3)
__global__ void attn_kernel(const unsigned short* __restrict__ Q,
                            const unsigned short* __restrict__ K,
                            const unsigned short* __restrict__ Vt,
                            unsigned short* __restrict__ O)
{
    constexpr int PST = 72;
    __shared__ unsigned short Ks[2][64 * 64];
    __shared__ unsigned short Vs[2][64 * 64];
    __shared__ unsigned short Pl[4 * 16 * PST];

    const int tid = threadIdx.x, lane = tid & 63, wid = tid >> 6;
    const int lrow = lane & 15, lk = lane >> 4;

    const int xcd = blockIdx.x & 7, loc = blockIdx.x >> 3;
    const int bh  = xcd * 8 + (loc & 7);
    const int qs  = 15 - (loc >> 3);
    const int b = bh >> 4, h = bh & 15;

    const unsigned short* Qb = Q  + (size_t)bh * Tc  * HSc;
    const unsigned short* Kb = K  + (size_t)bh * Tc  * HSc;
    const unsigned short* Vb = Vt + (size_t)bh * HSc * Tc;
    unsigned short* pl = &Pl[wid * 16 * PST];

    auto stage = [&](int buf, int kt) {
        const int kv0 = kt * 64;
        #pragma unroll
        for (int rr = 0; rr < 2; ++rr) {
            const int s   = ((rr * 4 + wid) << 6) + lane;
            const int row = s >> 3;
            const int gc  = (s & 7) ^ (row & 7);
            gload16(Kb + (size_t)(kv0 + row) * HSc + gc * 8, &Ks[buf][(rr * 4 + wid) << 9]);
            gload16(Vb + (size_t)row * Tc + kv0 + gc * 8,    &Vs[buf][(rr * 4 + wid) << 9]);
        }
    };

    constexpr float sc = 0.18033688011112042f;   // 0.125 * log2(e)

    const int wq0 = qs * 128 + wid * 32;
    const int ntile = 2 * qs + 2;

    bf16x8 qf[2][2];
    #pragma unroll
    for (int f = 0; f < 2; ++f)
        #pragma unroll
        for (int ks = 0; ks < 2; ++ks)
            qf[f][ks] = __builtin_bit_cast(bf16x8,
                *reinterpret_cast<const u16x8*>(Qb + (size_t)(wq0 + f * 16 + lrow) * HSc + ks * 32 + lk * 8));

    f32x4 Oacc[2][4] = {};
    float lsum[2][4] = {};

    stage(0, 0);
    for (int kt = 0; kt < ntile; ++kt) {
        const int kv0 = kt * 64;
        const int cur = kt & 1;
        const bool pre = (kt + 1 < ntile);
        if (pre) stage(cur ^ 1, kt + 1);
        if (pre) asm volatile("s_waitcnt vmcnt(4)" ::: "memory");
        else     asm volatile("s_waitcnt vmcnt(0)" ::: "memory");
        __builtin_amdgcn_s_barrier();

        if (kv0 <= wq0 + 31) {
            f32x4 S[2][4] = {};
            #pragma unroll
            for (int ct = 0; ct < 4; ++ct) {
                const int ro = ct * 16 + lrow;
                bf16x8 kf[2];
                #pragma unroll
                for (int ks = 0; ks < 2; ++ks)
                    kf[ks] = __builtin_bit_cast(bf16x8,
                        *reinterpret_cast<const u16x8*>(&Ks[cur][ro * 64 + (((ks * 4 + lk) ^ (ro & 7)) << 3)]));
                #pragma unroll
                for (int f = 0; f < 2; ++f)
                    #pragma unroll
                    for (int ks = 0; ks < 2; ++ks)
                        S[f][ct] = __builtin_amdgcn_mfma_f32_16x16x32_bf16(qf[f][ks], kf[ks], S[f][ct], 0, 0, 0);
            }

            bf16x8 pf[2][2];
            #pragma unroll
            for (int f = 0; f < 2; ++f) {
                const bool mf = (kv0 + 63 > wq0 + f * 16);
                #pragma unroll
                for (int ct = 0; ct < 4; ++ct)
                    #pragma unroll
                    for (int r = 0; r < 4; ++r) {
                        float s = S[f][ct][r] * sc;
                        if (mf && (kv0 + ct * 16 + lrow > wq0 + f * 16 + lk * 4 + r)) s = -1e30f;
                        float pv = __builtin_amdgcn_exp2f(s);
                        lsum[f][r] += pv;
                        pl[(lk * 4 + r) * PST + ct * 16 + lrow] =
                            __builtin_bit_cast(unsigned short, (__bf16)pv);
                    }
                asm volatile("s_waitcnt lgkmcnt(0)" ::: "memory");
                __builtin_amdgcn_sched_barrier(0);
                #pragma unroll
                for (int ks = 0; ks < 2; ++ks)
                    pf[f][ks] = __builtin_bit_cast(bf16x8,
                        *reinterpret_cast<const u16x8*>(&pl[lrow * PST + ks * 32 + lk * 8]));
                asm volatile("s_waitcnt lgkmcnt(0)" ::: "memory");
                __builtin_amdgcn_sched_barrier(0);
            }

            #pragma unroll
            for (int nt = 0; nt < 4; ++nt) {
                const int ro = nt * 16 + lrow;
                bf16x8 vf[2];
                #pragma unroll
                for (int ks = 0; ks < 2; ++ks)
                    vf[ks] = __builtin_bit_cast(bf16x8,
                        *reinterpret_cast<const u16x8*>(&Vs[cur][ro * 64 + (((ks * 4 + lk) ^ (ro & 7)) << 3)]));
                #pragma unroll
                for (int f = 0; f < 2; ++f)
                    #pragma unroll
                    for (int ks = 0; ks < 2; ++ks)
                        Oacc[f][nt] = __builtin_amdgcn_mfma_f32_16x16x32_bf16(pf[f][ks], vf[ks], Oacc[f][nt], 0, 0, 0);
            }
        }
        asm volatile("s_waitcnt lgkmcnt(0)" ::: "memory");
        __builtin_amdgcn_sched_barrier(0);
        __builtin_amdgcn_s_barrier();
    }

    #pragma unroll
    for (int f = 0; f < 2; ++f) {
        #pragma unroll
        for (int mk = 1; mk < 16; mk <<= 1)
            #pragma unroll
            for (int r = 0; r < 4; ++r) lsum[f][r] += __shfl_xor(lsum[f][r], mk, 64);
        #pragma unroll
        for (int r = 0; r < 4; ++r) {
            float inv = 1.0f / lsum[f][r];
            int t = wq0 + f * 16 + lk * 4 + r;
            #pragma unroll
            for (int nt = 0; nt < 4; ++nt) {
                int col = h * 64 + nt * 16 + lrow;
                O[((size_t)b * Tc + t) * Cc + col] = f2bf(Oacc[f][nt][r] * inv);
            }
        }
    }
}

// ---------------------------------------------------------------------------
extern "C" void kernel_launch(void* const* d_in, const int* in_sizes, int n_in,
                              void* d_out, int out_size, void* d_ws, size_t ws_size,
                              hipStream_t stream)
{
    const float* x    = (const float*)d_in[0];
    const float* Wqkv = (const float*)d_in[1];
    const float* bqkv = (const float*)d_in[2];
    const float* Wo   = (const float*)d_in[3];
    const float* bo   = (const float*)d_in[4];
    float* out = (float*)d_out;

    char* ws = (char*)d_ws;
    size_t off = 0;
    auto alloc = [&](size_t bytes) {
        void* p = ws + off;
        off += (bytes + 255) & ~(size_t)255;
        return p;
    };
    const size_t elems = (size_t)Bc * Hc * Tc * HSc;          // 8.4M
    unsigned short* Qb  = (unsigned short*)alloc(elems * 2);
    unsigned short* Kb  = (unsigned short*)alloc(elems * 2);
    unsigned short* Vt  = (unsigned short*)alloc(elems * 2);
    unsigned short* Oa  = (unsigned short*)alloc(elems * 2);
    unsigned short* Xb  = (unsigned short*)alloc((size_t)Mc * Kc * 2);      // x bf16
    unsigned short* Wq_t = (unsigned short*)alloc((size_t)N1c * Kc * 2);    // Wqkv^T bf16
    unsigned short* Wo_t = (unsigned short*)alloc((size_t)Cc * Kc * 2);     // Wo^T bf16
    f32x2* Rt = (f32x2*)alloc((size_t)Tc * 32 * 8);                          // rope table

    rope_tab_kernel<<<(Tc * 32) / 256, 256, 0, stream>>>(Rt);
    cvt_kernel<<<(Mc * Kc) / (256 * 8), 256, 0, stream>>>(x, Xb);
    wt_kernel<<<dim3(N1c / 64, Kc / 64), 256, 0, stream>>>(Wqkv, Wq_t, N1c, Kc);
    wt_kernel<<<dim3(Cc / 64, Kc / 64), 256, 0, stream>>>(Wo, Wo_t, Cc, Kc);

    // 1) QKV projection (8-phase 256^2) + fused table-RoPE + scatter; grid 384
    gemm8_kernel<<<(Mc / 256) * (N1c / 256), 512, 0, stream>>>(
        Xb, Wq_t, bqkv, Rt, Qb, Kb, Vt);
    // 2) causal flash attention (1024 blocks, XCD-local LPT)
    attn_kernel<<<1024, 256, 0, stream>>>(Qb, Kb, Vt, Oa);
    // 3) output projection -> fp32 d_out (grid 512)
    gemm1_kernel<<<(Cc / 128) * (Mc / 128), 256, 0, stream>>>(
        Oa, Wo_t, bo, out);
}

// Round 12
// 198.363 us; speedup vs baseline: 1.1265x; 1.1265x over previous
//
#include <hip/hip_runtime.h>
#include <math.h>

typedef float  f32x4 __attribute__((ext_vector_type(4)));
typedef float  f32x2 __attribute__((ext_vector_type(2)));
typedef __bf16 bf16x8 __attribute__((ext_vector_type(8)));
typedef unsigned short u16x8 __attribute__((ext_vector_type(8)));
typedef unsigned short u16x4 __attribute__((ext_vector_type(4)));

#define DEVI __device__ __forceinline__

constexpr int Bc = 4, Tc = 2048, Cc = 1024, Hc = 16, HSc = 64;
constexpr int Mc  = Bc * Tc;    // 8192 rows
constexpr int N1c = 3 * Cc;     // 3072 qkv cols
constexpr int Kc  = Cc;         // 1024 reduce dim

DEVI unsigned short f2bf(float f) {            // RNE fp32 -> bf16
    unsigned u = __builtin_bit_cast(unsigned, f);
    u += 0x7FFFu + ((u >> 16) & 1u);
    return (unsigned short)(u >> 16);
}
DEVI float bf2f(unsigned short s) {
    unsigned u = ((unsigned)s) << 16;
    return __builtin_bit_cast(float, u);
}

typedef const __attribute__((address_space(1))) void* gbl_vp;
typedef __attribute__((address_space(3))) void* lds_vp;
DEVI void gload16(const unsigned short* g, unsigned short* l) {
    __builtin_amdgcn_global_load_lds((gbl_vp)g, (lds_vp)l, 16, 0, 0);
}

// ---------------------------------------------------------------------------
// Prep 0: RoPE table  tab[t][d] = (cos(t*theta_d), sin(t*theta_d)), d=0..31
// ---------------------------------------------------------------------------
__global__ void rope_tab_kernel(f32x2* __restrict__ tab)
{
    const int i = blockIdx.x * blockDim.x + threadIdx.x;   // 0 .. 2048*32
    const int t = i >> 5, d = i & 31;
    float theta = exp2f(-(float)d * 0.41524101186186f);    // 10000^(-d/32)
    float s, c;
    sincosf((float)t * theta, &s, &c);
    f32x2 v; v[0] = c; v[1] = s;
    tab[i] = v;
}

// ---------------------------------------------------------------------------
// Prep 1: fp32 -> bf16 elementwise (x). 8 elems/thread.
// ---------------------------------------------------------------------------
__global__ void cvt_kernel(const float* __restrict__ in,
                           unsigned short* __restrict__ out)
{
    const size_t i = ((size_t)blockIdx.x * blockDim.x + threadIdx.x) * 8;
    f32x4 a = *reinterpret_cast<const f32x4*>(in + i);
    f32x4 b = *reinterpret_cast<const f32x4*>(in + i + 4);
    u16x8 o;
    o[0] = f2bf(a[0]); o[1] = f2bf(a[1]); o[2] = f2bf(a[2]); o[3] = f2bf(a[3]);
    o[4] = f2bf(b[0]); o[5] = f2bf(b[1]); o[6] = f2bf(b[2]); o[7] = f2bf(b[3]);
    *reinterpret_cast<u16x8*>(out + i) = o;
}

// ---------------------------------------------------------------------------
// Prep 2: W [K][N] fp32 -> Wt [N][K] bf16 (transpose + convert), 64x64 tiles.
// ---------------------------------------------------------------------------
__global__ void wt_kernel(const float* __restrict__ W,
                          unsigned short* __restrict__ Wt, int N, int K)
{
    __shared__ unsigned short Ts[64][72];
    const int tid = threadIdx.x;
    const int n0 = blockIdx.x * 64, k0 = blockIdx.y * 64;

    #pragma unroll
    for (int i = 0; i < 4; ++i) {
        int kr = (tid >> 4) + i * 16, nc = (tid & 15) * 4;
        f32x4 v = *reinterpret_cast<const f32x4*>(W + (size_t)(k0 + kr) * N + n0 + nc);
        #pragma unroll
        for (int e = 0; e < 4; ++e) Ts[kr][nc + e] = f2bf(v[e]);
    }
    __syncthreads();
    #pragma unroll
    for (int i = 0; i < 2; ++i) {
        int s = tid * 2 + i;
        int n = s >> 3, k8 = (s & 7) * 8;
        u16x8 o;
        #pragma unroll
        for (int j = 0; j < 8; ++j) o[j] = Ts[k8 + j][n];
        *reinterpret_cast<u16x8*>(Wt + (size_t)(n0 + n) * K + k0 + k8) = o;
    }
}

// ---------------------------------------------------------------------------
// bf16 GEMM (R10 proven core, 4x4 frag loop): C = A @ Bt^T + bias
// 128x128 tile, BK=64, 256 thr = 4 waves; global_load_lds w=16 staging with
// pre-swizzled source + XOR ds_read (0 bank conflicts).
// NEW: L2-locality block mapping — each XCD owns m-tiles [8*xcd, 8*xcd+8)
// (A slice 2 MB, L2-resident) x all n-tiles; consecutive blocks share one
// B-tile. Ideal per-XCD HBM fetch ~ A-slice + one pass of B.
// MODE 0: epilogue applies RoPE to Q/K via table lookup and scatters bf16
//         Q/K ([BH][T][HS]) and Vt ([BH][HS][T]).
// MODE 1: epilogue writes fp32 + bias to f_out.
// ---------------------------------------------------------------------------
template <int MODE, int NCOLS>
__global__ void gemm_kernel(const unsigned short* __restrict__ A,
                            const unsigned short* __restrict__ Bt,
                            const float* __restrict__ bias,
                            const f32x2* __restrict__ rope_t,
                            unsigned short* __restrict__ q_out,
                            unsigned short* __restrict__ k_out,
                            unsigned short* __restrict__ v_out,
                            float* __restrict__ f_out)
{
    __shared__ unsigned short As[128 * 64];
    __shared__ unsigned short Bs[128 * 64];

    const int tid  = threadIdx.x;
    const int lane = tid & 63, wid = tid >> 6;
    const int wr = wid >> 1, wc = wid & 1;
    const int lrow = lane & 15, lk = lane >> 4;

    // L2-locality mapping: xcd owns 8 m-tiles x all n-tiles, n-major groups of 8.
    const int xcd = blockIdx.x & 7, loc = blockIdx.x >> 3;
    const int m0 = (xcd * 8 + (loc & 7)) * 128;
    const int n0 = (loc >> 3) * 128;

    f32x4 acc[4][4] = {};

    for (int kt = 0; kt < Kc / 64; ++kt) {
        const int k0 = kt * 64;
        #pragma unroll
        for (int i = 0; i < 4; ++i) {
            const int s   = ((i * 4 + wid) << 6) + lane;
            const int row = s >> 3;
            const int gc  = (s & 7) ^ (row & 7);
            gload16(A  + (size_t)(m0 + row) * Kc + k0 + gc * 8, &As[(i * 4 + wid) << 9]);
            gload16(Bt + (size_t)(n0 + row) * Kc + k0 + gc * 8, &Bs[(i * 4 + wid) << 9]);
        }
        __syncthreads();

        #pragma unroll
        for (int kk = 0; kk < 2; ++kk) {
            bf16x8 a[4], b[4];
            #pragma unroll
            for (int mt = 0; mt < 4; ++mt) {
                const int ra = wr * 64 + mt * 16 + lrow;
                a[mt] = __builtin_bit_cast(bf16x8,
                    *reinterpret_cast<const u16x8*>(&As[ra * 64 + (((kk * 4 + lk) ^ (ra & 7)) << 3)]));
            }
            #pragma unroll
            for (int nt = 0; nt < 4; ++nt) {
                const int rb = wc * 64 + nt * 16 + lrow;
                b[nt] = __builtin_bit_cast(bf16x8,
                    *reinterpret_cast<const u16x8*>(&Bs[rb * 64 + (((kk * 4 + lk) ^ (rb & 7)) << 3)]));
            }
            #pragma unroll
            for (int mt = 0; mt < 4; ++mt)
                #pragma unroll
                for (int nt = 0; nt < 4; ++nt)
                    acc[mt][nt] = __builtin_amdgcn_mfma_f32_16x16x32_bf16(a[mt], b[nt], acc[mt][nt], 0, 0, 0);
        }
        __syncthreads();
    }

    // ---- epilogue ----
    #pragma unroll
    for (int mt = 0; mt < 4; ++mt) {
        #pragma unroll
        for (int nt = 0; nt < 4; ++nt) {
            #pragma unroll
            for (int r = 0; r < 4; ++r) {
                int grow = m0 + wr * 64 + mt * 16 + lk * 4 + r;
                int gcol = n0 + wc * 64 + nt * 16 + lrow;
                float val = acc[mt][nt][r] + bias[gcol];
                if constexpr (MODE == 0) {
                    int tsel = gcol >> 10;            // 0:q 1:k 2:v  (block-uniform)
                    int cc   = gcol & 1023;
                    int h    = cc >> 6, hs = cc & 63;
                    int bb   = grow >> 11, t = grow & (Tc - 1);
                    int bh   = bb * Hc + h;
                    if (tsel == 2) {
                        v_out[((size_t)bh * HSc + hs) * Tc + t] = f2bf(val);
                    } else {
                        // fused RoPE: pair (x[2d], x[2d+1]) in adjacent lanes.
                        float partner = __shfl_xor(val, 1, 64);
                        const bool ev = !(lrow & 1);
                        float x1 = ev ? val : partner;
                        float x2 = ev ? partner : val;
                        int d = hs >> 1;
                        f32x2 cs = rope_t[t * 32 + d];    // L1-hot 8B lookup
                        float o = ev ? (x1 * cs[0] - x2 * cs[1])
                                     : (x1 * cs[1] + x2 * cs[0]);
                        int hs_out = ev ? d : d + 32;
                        unsigned short* dst = (tsel == 0) ? q_out : k_out;
                        dst[((size_t)bh * Tc + t) * HSc + hs_out] = f2bf(o);
                    }
                } else {
                    f_out[(size_t)grow * Cc + gcol] = val;
                }
            }
        }
    }
}

// ---------------------------------------------------------------------------
// Causal flash attention v6 (R10 proven): wave = 32 q-rows, K/V frag reuse,
// dbuf + counted vmcnt(4), no running max, deferred row-sum, XCD-local LPT,
// sequential-f P buffer -> 3 blocks/CU.
// ---------------------------------------------------------------------------
__launch_bounds__(256, 3)
__global__ void attn_kernel(const unsigned short* __restrict__ Q,
                            const unsigned short* __restrict__ K,
                            const unsigned short* __restrict__ Vt,
                            unsigned short* __restrict__ O)
{
    constexpr int PST = 72;
    __shared__ unsigned short Ks[2][64 * 64];
    __shared__ unsigned short Vs[2][64 * 64];
    __shared__ unsigned short Pl[4 * 16 * PST];

    const int tid = threadIdx.x, lane = tid & 63, wid = tid >> 6;
    const int lrow = lane & 15, lk = lane >> 4;

    const int xcd = blockIdx.x & 7, loc = blockIdx.x >> 3;
    const int bh  = xcd * 8 + (loc & 7);
    const int qs  = 15 - (loc >> 3);
    const int b = bh >> 4, h = bh & 15;

    const unsigned short* Qb = Q  + (size_t)bh * Tc  * HSc;
    const unsigned short* Kb = K  + (size_t)bh * Tc  * HSc;
    const unsigned short* Vb = Vt + (size_t)bh * HSc * Tc;
    unsigned short* pl = &Pl[wid * 16 * PST];

    auto stage = [&](int buf, int kt) {
        const int kv0 = kt * 64;
        #pragma unroll
        for (int rr = 0; rr < 2; ++rr) {
            const int s   = ((rr * 4 + wid) << 6) + lane;
            const int row = s >> 3;
            const int gc  = (s & 7) ^ (row & 7);
            gload16(Kb + (size_t)(kv0 + row) * HSc + gc * 8, &Ks[buf][(rr * 4 + wid) << 9]);
            gload16(Vb + (size_t)row * Tc + kv0 + gc * 8,    &Vs[buf][(rr * 4 + wid) << 9]);
        }
    };

    constexpr float sc = 0.18033688011112042f;   // 0.125 * log2(e)

    const int wq0 = qs * 128 + wid * 32;
    const int ntile = 2 * qs + 2;

    bf16x8 qf[2][2];
    #pragma unroll
    for (int f = 0; f < 2; ++f)
        #pragma unroll
        for (int ks = 0; ks < 2; ++ks)
            qf[f][ks] = __builtin_bit_cast(bf16x8,
                *reinterpret_cast<const u16x8*>(Qb + (size_t)(wq0 + f * 16 + lrow) * HSc + ks * 32 + lk * 8));

    f32x4 Oacc[2][4] = {};
    float lsum[2][4] = {};

    stage(0, 0);
    for (int kt = 0; kt < ntile; ++kt) {
        const int kv0 = kt * 64;
        const int cur = kt & 1;
        const bool pre = (kt + 1 < ntile);
        if (pre) stage(cur ^ 1, kt + 1);
        if (pre) asm volatile("s_waitcnt vmcnt(4)" ::: "memory");
        else     asm volatile("s_waitcnt vmcnt(0)" ::: "memory");
        __builtin_amdgcn_s_barrier();

        if (kv0 <= wq0 + 31) {
            f32x4 S[2][4] = {};
            #pragma unroll
            for (int ct = 0; ct < 4; ++ct) {
                const int ro = ct * 16 + lrow;
                bf16x8 kf[2];
                #pragma unroll
                for (int ks = 0; ks < 2; ++ks)
                    kf[ks] = __builtin_bit_cast(bf16x8,
                        *reinterpret_cast<const u16x8*>(&Ks[cur][ro * 64 + (((ks * 4 + lk) ^ (ro & 7)) << 3)]));
                #pragma unroll
                for (int f = 0; f < 2; ++f)
                    #pragma unroll
                    for (int ks = 0; ks < 2; ++ks)
                        S[f][ct] = __builtin_amdgcn_mfma_f32_16x16x32_bf16(qf[f][ks], kf[ks], S[f][ct], 0, 0, 0);
            }

            bf16x8 pf[2][2];
            #pragma unroll
            for (int f = 0; f < 2; ++f) {
                const bool mf = (kv0 + 63 > wq0 + f * 16);
                #pragma unroll
                for (int ct = 0; ct < 4; ++ct)
                    #pragma unroll
                    for (int r = 0; r < 4; ++r) {
                        float s = S[f][ct][r] * sc;
                        if (mf && (kv0 + ct * 16 + lrow > wq0 + f * 16 + lk * 4 + r)) s = -1e30f;
                        float pv = __builtin_amdgcn_exp2f(s);
                        lsum[f][r] += pv;
                        pl[(lk * 4 + r) * PST + ct * 16 + lrow] =
                            __builtin_bit_cast(unsigned short, (__bf16)pv);
                    }
                asm volatile("s_waitcnt lgkmcnt(0)" ::: "memory");
                __builtin_amdgcn_sched_barrier(0);
                #pragma unroll
                for (int ks = 0; ks < 2; ++ks)
                    pf[f][ks] = __builtin_bit_cast(bf16x8,
                        *reinterpret_cast<const u16x8*>(&pl[lrow * PST + ks * 32 + lk * 8]));
                asm volatile("s_waitcnt lgkmcnt(0)" ::: "memory");
                __builtin_amdgcn_sched_barrier(0);
            }

            #pragma unroll
            for (int nt = 0; nt < 4; ++nt) {
                const int ro = nt * 16 + lrow;
                bf16x8 vf[2];
                #pragma unroll
                for (int ks = 0; ks < 2; ++ks)
                    vf[ks] = __builtin_bit_cast(bf16x8,
                        *reinterpret_cast<const u16x8*>(&Vs[cur][ro * 64 + (((ks * 4 + lk) ^ (ro & 7)) << 3)]));
                #pragma unroll
                for (int f = 0; f < 2; ++f)
                    #pragma unroll
                    for (int ks = 0; ks < 2; ++ks)
                        Oacc[f][nt] = __builtin_amdgcn_mfma_f32_16x16x32_bf16(pf[f][ks], vf[ks], Oacc[f][nt], 0, 0, 0);
            }
        }
        asm volatile("s_waitcnt lgkmcnt(0)" ::: "memory");
        __builtin_amdgcn_sched_barrier(0);
        __builtin_amdgcn_s_barrier();
    }

    #pragma unroll
    for (int f = 0; f < 2; ++f) {
        #pragma unroll
        for (int mk = 1; mk < 16; mk <<= 1)
            #pragma unroll
            for (int r = 0; r < 4; ++r) lsum[f][r] += __shfl_xor(lsum[f][r], mk, 64);
        #pragma unroll
        for (int r = 0; r < 4; ++r) {
            float inv = 1.0f / lsum[f][r];
            int t = wq0 + f * 16 + lk * 4 + r;
            #pragma unroll
            for (int nt = 0; nt < 4; ++nt) {
                int col = h * 64 + nt * 16 + lrow;
                O[((size_t)b * Tc + t) * Cc + col] = f2bf(Oacc[f][nt][r] * inv);
            }
        }
    }
}

// ---------------------------------------------------------------------------
extern "C" void kernel_launch(void* const* d_in, const int* in_sizes, int n_in,
                              void* d_out, int out_size, void* d_ws, size_t ws_size,
                              hipStream_t stream)
{
    const float* x    = (const float*)d_in[0];
    const float* Wqkv = (const float*)d_in[1];
    const float* bqkv = (const float*)d_in[2];
    const float* Wo   = (const float*)d_in[3];
    const float* bo   = (const float*)d_in[4];
    float* out = (float*)d_out;

    char* ws = (char*)d_ws;
    size_t off = 0;
    auto alloc = [&](size_t bytes) {
        void* p = ws + off;
        off += (bytes + 255) & ~(size_t)255;
        return p;
    };
    const size_t elems = (size_t)Bc * Hc * Tc * HSc;          // 8.4M
    unsigned short* Qb  = (unsigned short*)alloc(elems * 2);
    unsigned short* Kb  = (unsigned short*)alloc(elems * 2);
    unsigned short* Vt  = (unsigned short*)alloc(elems * 2);
    unsigned short* Oa  = (unsigned short*)alloc(elems * 2);
    unsigned short* Xb  = (unsigned short*)alloc((size_t)Mc * Kc * 2);      // x bf16
    unsigned short* Wq_t = (unsigned short*)alloc((size_t)N1c * Kc * 2);    // Wqkv^T bf16
    unsigned short* Wo_t = (unsigned short*)alloc((size_t)Cc * Kc * 2);     // Wo^T bf16
    f32x2* Rt = (f32x2*)alloc((size_t)Tc * 32 * 8);                          // rope table

    rope_tab_kernel<<<(Tc * 32) / 256, 256, 0, stream>>>(Rt);
    cvt_kernel<<<(Mc * Kc) / (256 * 8), 256, 0, stream>>>(x, Xb);
    wt_kernel<<<dim3(N1c / 64, Kc / 64), 256, 0, stream>>>(Wqkv, Wq_t, N1c, Kc);
    wt_kernel<<<dim3(Cc / 64, Kc / 64), 256, 0, stream>>>(Wo, Wo_t, Cc, Kc);

    // 1) QKV projection + fused table-RoPE + scatter (grid 1536)
    gemm_kernel<0, N1c><<<(N1c / 128) * (Mc / 128), 256, 0, stream>>>(
        Xb, Wq_t, bqkv, Rt, Qb, Kb, Vt, nullptr);
    // 2) causal flash attention (1024 blocks, XCD-local LPT)
    attn_kernel<<<1024, 256, 0, stream>>>(Qb, Kb, Vt, Oa);
    // 3) output projection -> fp32 d_out (grid 512)
    gemm_kernel<1, Cc><<<(Cc / 128) * (Mc / 128), 256, 0, stream>>>(
        Oa, Wo_t, bo, nullptr, nullptr, nullptr, nullptr, out);
}

// Round 13
// 184.311 us; speedup vs baseline: 1.2124x; 1.0762x over previous
//
#include <hip/hip_runtime.h>
#include <math.h>

typedef float  f32x4 __attribute__((ext_vector_type(4)));
typedef float  f32x2 __attribute__((ext_vector_type(2)));
typedef __bf16 bf16x8 __attribute__((ext_vector_type(8)));
typedef unsigned short u16x8 __attribute__((ext_vector_type(8)));
typedef unsigned short u16x4 __attribute__((ext_vector_type(4)));

#define DEVI __device__ __forceinline__

constexpr int Bc = 4, Tc = 2048, Cc = 1024, Hc = 16, HSc = 64;
constexpr int Mc  = Bc * Tc;    // 8192 rows
constexpr int N1c = 3 * Cc;     // 3072 qkv cols
constexpr int Kc  = Cc;         // 1024 reduce dim

DEVI unsigned short f2bf(float f) {            // RNE fp32 -> bf16
    unsigned u = __builtin_bit_cast(unsigned, f);
    u += 0x7FFFu + ((u >> 16) & 1u);
    return (unsigned short)(u >> 16);
}
DEVI float bf2f(unsigned short s) {
    unsigned u = ((unsigned)s) << 16;
    return __builtin_bit_cast(float, u);
}

typedef const __attribute__((address_space(1))) void* gbl_vp;
typedef __attribute__((address_space(3))) void* lds_vp;
DEVI void gload16(const unsigned short* g, unsigned short* l) {
    __builtin_amdgcn_global_load_lds((gbl_vp)g, (lds_vp)l, 16, 0, 0);
}

// ---------------------------------------------------------------------------
// Prep 0: RoPE table  tab[t][d] = (cos(t*theta_d), sin(t*theta_d)), d=0..31
// ---------------------------------------------------------------------------
__global__ void rope_tab_kernel(f32x2* __restrict__ tab)
{
    const int i = blockIdx.x * blockDim.x + threadIdx.x;   // 0 .. 2048*32
    const int t = i >> 5, d = i & 31;
    float theta = exp2f(-(float)d * 0.41524101186186f);    // 10000^(-d/32)
    float s, c;
    sincosf((float)t * theta, &s, &c);
    f32x2 v; v[0] = c; v[1] = s;
    tab[i] = v;
}

// ---------------------------------------------------------------------------
// Prep 1: fp32 -> bf16 elementwise (x). 8 elems/thread.
// ---------------------------------------------------------------------------
__global__ void cvt_kernel(const float* __restrict__ in,
                           unsigned short* __restrict__ out)
{
    const size_t i = ((size_t)blockIdx.x * blockDim.x + threadIdx.x) * 8;
    f32x4 a = *reinterpret_cast<const f32x4*>(in + i);
    f32x4 b = *reinterpret_cast<const f32x4*>(in + i + 4);
    u16x8 o;
    o[0] = f2bf(a[0]); o[1] = f2bf(a[1]); o[2] = f2bf(a[2]); o[3] = f2bf(a[3]);
    o[4] = f2bf(b[0]); o[5] = f2bf(b[1]); o[6] = f2bf(b[2]); o[7] = f2bf(b[3]);
    *reinterpret_cast<u16x8*>(out + i) = o;
}

// ---------------------------------------------------------------------------
// Prep 2: W [K][N] fp32 -> Wt [N][K] bf16 (transpose + convert), 64x64 tiles.
// ---------------------------------------------------------------------------
__global__ void wt_kernel(const float* __restrict__ W,
                          unsigned short* __restrict__ Wt, int N, int K)
{
    __shared__ unsigned short Ts[64][72];
    const int tid = threadIdx.x;
    const int n0 = blockIdx.x * 64, k0 = blockIdx.y * 64;

    #pragma unroll
    for (int i = 0; i < 4; ++i) {
        int kr = (tid >> 4) + i * 16, nc = (tid & 15) * 4;
        f32x4 v = *reinterpret_cast<const f32x4*>(W + (size_t)(k0 + kr) * N + n0 + nc);
        #pragma unroll
        for (int e = 0; e < 4; ++e) Ts[kr][nc + e] = f2bf(v[e]);
    }
    __syncthreads();
    #pragma unroll
    for (int i = 0; i < 2; ++i) {
        int s = tid * 2 + i;
        int n = s >> 3, k8 = (s & 7) * 8;
        u16x8 o;
        #pragma unroll
        for (int j = 0; j < 8; ++j) o[j] = Ts[k8 + j][n];
        *reinterpret_cast<u16x8*>(Wt + (size_t)(n0 + n) * K + k0 + k8) = o;
    }
}

// ---------------------------------------------------------------------------
// bf16 GEMM (R12 proven core): C = A @ Bt^T + bias
// 128x128 tile, BK=64, 256 thr = 4 waves; global_load_lds w=16 staging with
// pre-swizzled source + XOR ds_read (0 conflicts). L2-locality mapping:
// each XCD owns 8 m-tiles (A slice 2 MB L2-resident) x all n-tiles.
// MODE 0: Q/K -> fused table-RoPE scatter; V -> LDS-transposed COALESCED
//         16B stores (NEW: was 64 scattered 2B stores/thread).
// MODE 1: fp32 + bias to f_out.
// ---------------------------------------------------------------------------
template <int MODE, int NCOLS>
__global__ void gemm_kernel(const unsigned short* __restrict__ A,
                            const unsigned short* __restrict__ Bt,
                            const float* __restrict__ bias,
                            const f32x2* __restrict__ rope_t,
                            unsigned short* __restrict__ q_out,
                            unsigned short* __restrict__ k_out,
                            unsigned short* __restrict__ v_out,
                            float* __restrict__ f_out)
{
    __shared__ unsigned short SM[2 * 128 * 64];   // As | Bs ; reused as Tv
    unsigned short* As = SM;
    unsigned short* Bs = SM + 128 * 64;

    const int tid  = threadIdx.x;
    const int lane = tid & 63, wid = tid >> 6;
    const int wr = wid >> 1, wc = wid & 1;
    const int lrow = lane & 15, lk = lane >> 4;

    // L2-locality mapping: xcd owns 8 m-tiles x all n-tiles.
    const int xcd = blockIdx.x & 7, loc = blockIdx.x >> 3;
    const int m0 = (xcd * 8 + (loc & 7)) * 128;
    const int n0 = (loc >> 3) * 128;

    f32x4 acc[4][4] = {};

    for (int kt = 0; kt < Kc / 64; ++kt) {
        const int k0 = kt * 64;
        #pragma unroll
        for (int i = 0; i < 4; ++i) {
            const int s   = ((i * 4 + wid) << 6) + lane;
            const int row = s >> 3;
            const int gc  = (s & 7) ^ (row & 7);
            gload16(A  + (size_t)(m0 + row) * Kc + k0 + gc * 8, &As[(i * 4 + wid) << 9]);
            gload16(Bt + (size_t)(n0 + row) * Kc + k0 + gc * 8, &Bs[(i * 4 + wid) << 9]);
        }
        __syncthreads();

        #pragma unroll
        for (int kk = 0; kk < 2; ++kk) {
            bf16x8 a[4], b[4];
            #pragma unroll
            for (int mt = 0; mt < 4; ++mt) {
                const int ra = wr * 64 + mt * 16 + lrow;
                a[mt] = __builtin_bit_cast(bf16x8,
                    *reinterpret_cast<const u16x8*>(&As[ra * 64 + (((kk * 4 + lk) ^ (ra & 7)) << 3)]));
            }
            #pragma unroll
            for (int nt = 0; nt < 4; ++nt) {
                const int rb = wc * 64 + nt * 16 + lrow;
                b[nt] = __builtin_bit_cast(bf16x8,
                    *reinterpret_cast<const u16x8*>(&Bs[rb * 64 + (((kk * 4 + lk) ^ (rb & 7)) << 3)]));
            }
            #pragma unroll
            for (int mt = 0; mt < 4; ++mt)
                #pragma unroll
                for (int nt = 0; nt < 4; ++nt)
                    acc[mt][nt] = __builtin_amdgcn_mfma_f32_16x16x32_bf16(a[mt], b[nt], acc[mt][nt], 0, 0, 0);
        }
        __syncthreads();
    }

    // ---- epilogue ----
    if constexpr (MODE == 1) {
        #pragma unroll
        for (int mt = 0; mt < 4; ++mt)
            #pragma unroll
            for (int nt = 0; nt < 4; ++nt)
                #pragma unroll
                for (int r = 0; r < 4; ++r) {
                    int grow = m0 + wr * 64 + mt * 16 + lk * 4 + r;
                    int gcol = n0 + wc * 64 + nt * 16 + lrow;
                    f_out[(size_t)grow * Cc + gcol] = acc[mt][nt][r] + bias[gcol];
                }
    } else if (n0 >= 2 * Cc) {
        // ---- V: transpose via LDS (stride 136, 16B-aligned rows), 2 passes
        unsigned short* Tv = SM;                  // 64 x 136 u16 = 17.4 KB
        const int bb = m0 >> 11, t0 = m0 & (Tc - 1);
        #pragma unroll
        for (int p = 0; p < 2; ++p) {
            if (wc == p) {
                #pragma unroll
                for (int mt = 0; mt < 4; ++mt)
                    #pragma unroll
                    for (int nt = 0; nt < 4; ++nt)
                        #pragma unroll
                        for (int r = 0; r < 4; ++r) {
                            int hs_l = nt * 16 + lrow;
                            int t_l  = wr * 64 + mt * 16 + lk * 4 + r;
                            int gcol = n0 + wc * 64 + nt * 16 + lrow;
                            Tv[hs_l * 136 + t_l] = f2bf(acc[mt][nt][r] + bias[gcol]);
                        }
            }
            __syncthreads();
            const int h  = ((n0 - 2 * Cc) >> 6) + p;     // head 0..15
            const int bh = bb * Hc + h;
            #pragma unroll
            for (int i = 0; i < 4; ++i) {
                int ch = i * 256 + tid;                  // 0..1023 chunks of 8
                int hs = ch >> 4, tc = ch & 15;
                u16x8 v = *reinterpret_cast<const u16x8*>(&Tv[hs * 136 + tc * 8]);
                *reinterpret_cast<u16x8*>(
                    &v_out[((size_t)bh * HSc + hs) * Tc + t0 + tc * 8]) = v;
            }
            __syncthreads();
        }
    } else {
        // ---- Q/K: fused table-RoPE scatter (dst block-uniform)
        unsigned short* dst = (n0 < Cc) ? q_out : k_out;
        #pragma unroll
        for (int mt = 0; mt < 4; ++mt)
            #pragma unroll
            for (int nt = 0; nt < 4; ++nt)
                #pragma unroll
                for (int r = 0; r < 4; ++r) {
                    int grow = m0 + wr * 64 + mt * 16 + lk * 4 + r;
                    int gcol = n0 + wc * 64 + nt * 16 + lrow;
                    float val = acc[mt][nt][r] + bias[gcol];
                    int cc   = gcol & (Cc - 1);
                    int h    = cc >> 6, hs = cc & 63;
                    int bb   = grow >> 11, t = grow & (Tc - 1);
                    int bh   = bb * Hc + h;
                    float partner = __shfl_xor(val, 1, 64);
                    const bool ev = !(lrow & 1);
                    float x1 = ev ? val : partner;
                    float x2 = ev ? partner : val;
                    int d = hs >> 1;
                    f32x2 cs = rope_t[t * 32 + d];
                    float o = ev ? (x1 * cs[0] - x2 * cs[1])
                                 : (x1 * cs[1] + x2 * cs[0]);
                    int hs_out = ev ? d : d + 32;
                    dst[((size_t)bh * Tc + t) * HSc + hs_out] = f2bf(o);
                }
    }
}

// ---------------------------------------------------------------------------
// Causal flash attention v7: v6 grid/LPT + v5's 32-row P buffer (write both
// f-blocks, ONE lgkmcnt drain, read both; inner drains removed — tile-end
// drain guards overwrite). LDS 51.2 KB -> still 3 blocks/CU.
// ---------------------------------------------------------------------------
__launch_bounds__(256, 3)
__global__ void attn_kernel(const unsigned short* __restrict__ Q,
                            const unsigned short* __restrict__ K,
                            const unsigned short* __restrict__ Vt,
                            unsigned short* __restrict__ O)
{
    constexpr int PST = 72;
    __shared__ unsigned short Ks[2][64 * 64];
    __shared__ unsigned short Vs[2][64 * 64];
    __shared__ unsigned short Pl[4 * 32 * PST];   // 32 P-rows per wave

    const int tid = threadIdx.x, lane = tid & 63, wid = tid >> 6;
    const int lrow = lane & 15, lk = lane >> 4;

    const int xcd = blockIdx.x & 7, loc = blockIdx.x >> 3;
    const int bh  = xcd * 8 + (loc & 7);
    const int qs  = 15 - (loc >> 3);
    const int b = bh >> 4, h = bh & 15;

    const unsigned short* Qb = Q  + (size_t)bh * Tc  * HSc;
    const unsigned short* Kb = K  + (size_t)bh * Tc  * HSc;
    const unsigned short* Vb = Vt + (size_t)bh * HSc * Tc;
    unsigned short* pl = &Pl[wid * 32 * PST];

    auto stage = [&](int buf, int kt) {
        const int kv0 = kt * 64;
        #pragma unroll
        for (int rr = 0; rr < 2; ++rr) {
            const int s   = ((rr * 4 + wid) << 6) + lane;
            const int row = s >> 3;
            const int gc  = (s & 7) ^ (row & 7);
            gload16(Kb + (size_t)(kv0 + row) * HSc + gc * 8, &Ks[buf][(rr * 4 + wid) << 9]);
            gload16(Vb + (size_t)row * Tc + kv0 + gc * 8,    &Vs[buf][(rr * 4 + wid) << 9]);
        }
    };

    constexpr float sc = 0.18033688011112042f;   // 0.125 * log2(e)

    const int wq0 = qs * 128 + wid * 32;
    const int ntile = 2 * qs + 2;

    bf16x8 qf[2][2];
    #pragma unroll
    for (int f = 0; f < 2; ++f)
        #pragma unroll
        for (int ks = 0; ks < 2; ++ks)
            qf[f][ks] = __builtin_bit_cast(bf16x8,
                *reinterpret_cast<const u16x8*>(Qb + (size_t)(wq0 + f * 16 + lrow) * HSc + ks * 32 + lk * 8));

    f32x4 Oacc[2][4] = {};
    float lsum[2][4] = {};

    stage(0, 0);
    for (int kt = 0; kt < ntile; ++kt) {
        const int kv0 = kt * 64;
        const int cur = kt & 1;
        const bool pre = (kt + 1 < ntile);
        if (pre) stage(cur ^ 1, kt + 1);
        if (pre) asm volatile("s_waitcnt vmcnt(4)" ::: "memory");
        else     asm volatile("s_waitcnt vmcnt(0)" ::: "memory");
        __builtin_amdgcn_s_barrier();

        if (kv0 <= wq0 + 31) {
            f32x4 S[2][4] = {};
            #pragma unroll
            for (int ct = 0; ct < 4; ++ct) {
                const int ro = ct * 16 + lrow;
                bf16x8 kf[2];
                #pragma unroll
                for (int ks = 0; ks < 2; ++ks)
                    kf[ks] = __builtin_bit_cast(bf16x8,
                        *reinterpret_cast<const u16x8*>(&Ks[cur][ro * 64 + (((ks * 4 + lk) ^ (ro & 7)) << 3)]));
                #pragma unroll
                for (int f = 0; f < 2; ++f)
                    #pragma unroll
                    for (int ks = 0; ks < 2; ++ks)
                        S[f][ct] = __builtin_amdgcn_mfma_f32_16x16x32_bf16(qf[f][ks], kf[ks], S[f][ct], 0, 0, 0);
            }

            // ---- P = exp2(S*sc), diag-masked; write BOTH f, one drain
            #pragma unroll
            for (int f = 0; f < 2; ++f) {
                const bool mf = (kv0 + 63 > wq0 + f * 16);
                #pragma unroll
                for (int ct = 0; ct < 4; ++ct)
                    #pragma unroll
                    for (int r = 0; r < 4; ++r) {
                        float s = S[f][ct][r] * sc;
                        if (mf && (kv0 + ct * 16 + lrow > wq0 + f * 16 + lk * 4 + r)) s = -1e30f;
                        float pv = __builtin_amdgcn_exp2f(s);
                        lsum[f][r] += pv;
                        pl[(f * 16 + lk * 4 + r) * PST + ct * 16 + lrow] =
                            __builtin_bit_cast(unsigned short, (__bf16)pv);
                    }
            }
            asm volatile("s_waitcnt lgkmcnt(0)" ::: "memory");
            __builtin_amdgcn_sched_barrier(0);
            bf16x8 pf[2][2];
            #pragma unroll
            for (int f = 0; f < 2; ++f)
                #pragma unroll
                for (int ks = 0; ks < 2; ++ks)
                    pf[f][ks] = __builtin_bit_cast(bf16x8,
                        *reinterpret_cast<const u16x8*>(&pl[(f * 16 + lrow) * PST + ks * 32 + lk * 8]));

            #pragma unroll
            for (int nt = 0; nt < 4; ++nt) {
                const int ro = nt * 16 + lrow;
                bf16x8 vf[2];
                #pragma unroll
                for (int ks = 0; ks < 2; ++ks)
                    vf[ks] = __builtin_bit_cast(bf16x8,
                        *reinterpret_cast<const u16x8*>(&Vs[cur][ro * 64 + (((ks * 4 + lk) ^ (ro & 7)) << 3)]));
                #pragma unroll
                for (int f = 0; f < 2; ++f)
                    #pragma unroll
                    for (int ks = 0; ks < 2; ++ks)
                        Oacc[f][nt] = __builtin_amdgcn_mfma_f32_16x16x32_bf16(pf[f][ks], vf[ks], Oacc[f][nt], 0, 0, 0);
            }
        }
        asm volatile("s_waitcnt lgkmcnt(0)" ::: "memory");   // all LDS reads landed
        __builtin_amdgcn_sched_barrier(0);
        __builtin_amdgcn_s_barrier();         // safe to overwrite bufs
    }

    #pragma unroll
    for (int f = 0; f < 2; ++f) {
        #pragma unroll
        for (int mk = 1; mk < 16; mk <<= 1)
            #pragma unroll
            for (int r = 0; r < 4; ++r) lsum[f][r] += __shfl_xor(lsum[f][r], mk, 64);
        #pragma unroll
        for (int r = 0; r < 4; ++r) {
            float inv = 1.0f / lsum[f][r];
            int t = wq0 + f * 16 + lk * 4 + r;
            #pragma unroll
            for (int nt = 0; nt < 4; ++nt) {
                int col = h * 64 + nt * 16 + lrow;
                O[((size_t)b * Tc + t) * Cc + col] = f2bf(Oacc[f][nt][r] * inv);
            }
        }
    }
}

// ---------------------------------------------------------------------------
extern "C" void kernel_launch(void* const* d_in, const int* in_sizes, int n_in,
                              void* d_out, int out_size, void* d_ws, size_t ws_size,
                              hipStream_t stream)
{
    const float* x    = (const float*)d_in[0];
    const float* Wqkv = (const float*)d_in[1];
    const float* bqkv = (const float*)d_in[2];
    const float* Wo   = (const float*)d_in[3];
    const float* bo   = (const float*)d_in[4];
    float* out = (float*)d_out;

    char* ws = (char*)d_ws;
    size_t off = 0;
    auto alloc = [&](size_t bytes) {
        void* p = ws + off;
        off += (bytes + 255) & ~(size_t)255;
        return p;
    };
    const size_t elems = (size_t)Bc * Hc * Tc * HSc;          // 8.4M
    unsigned short* Qb  = (unsigned short*)alloc(elems * 2);
    unsigned short* Kb  = (unsigned short*)alloc(elems * 2);
    unsigned short* Vt  = (unsigned short*)alloc(elems * 2);
    unsigned short* Oa  = (unsigned short*)alloc(elems * 2);
    unsigned short* Xb  = (unsigned short*)alloc((size_t)Mc * Kc * 2);      // x bf16
    unsigned short* Wq_t = (unsigned short*)alloc((size_t)N1c * Kc * 2);    // Wqkv^T bf16
    unsigned short* Wo_t = (unsigned short*)alloc((size_t)Cc * Kc * 2);     // Wo^T bf16
    f32x2* Rt = (f32x2*)alloc((size_t)Tc * 32 * 8);                          // rope table

    rope_tab_kernel<<<(Tc * 32) / 256, 256, 0, stream>>>(Rt);
    cvt_kernel<<<(Mc * Kc) / (256 * 8), 256, 0, stream>>>(x, Xb);
    wt_kernel<<<dim3(N1c / 64, Kc / 64), 256, 0, stream>>>(Wqkv, Wq_t, N1c, Kc);
    wt_kernel<<<dim3(Cc / 64, Kc / 64), 256, 0, stream>>>(Wo, Wo_t, Cc, Kc);

    // 1) QKV projection + fused table-RoPE + coalesced-V scatter (grid 1536)
    gemm_kernel<0, N1c><<<(N1c / 128) * (Mc / 128), 256, 0, stream>>>(
        Xb, Wq_t, bqkv, Rt, Qb, Kb, Vt, nullptr);
    // 2) causal flash attention (1024 blocks, XCD-local LPT)
    attn_kernel<<<1024, 256, 0, stream>>>(Qb, Kb, Vt, Oa);
    // 3) output projection -> fp32 d_out (grid 512)
    gemm_kernel<1, Cc><<<(Cc / 128) * (Mc / 128), 256, 0, stream>>>(
        Oa, Wo_t, bo, nullptr, nullptr, nullptr, nullptr, out);
}

// Round 14
// 174.467 us; speedup vs baseline: 1.2808x; 1.0564x over previous
//
#include <hip/hip_runtime.h>
#include <math.h>

typedef float  f32x4 __attribute__((ext_vector_type(4)));
typedef float  f32x2 __attribute__((ext_vector_type(2)));
typedef __bf16 bf16x8 __attribute__((ext_vector_type(8)));
typedef unsigned short u16x8 __attribute__((ext_vector_type(8)));
typedef unsigned short u16x4 __attribute__((ext_vector_type(4)));

#define DEVI __device__ __forceinline__

constexpr int Bc = 4, Tc = 2048, Cc = 1024, Hc = 16, HSc = 64;
constexpr int Mc  = Bc * Tc;    // 8192 rows
constexpr int N1c = 3 * Cc;     // 3072 qkv cols
constexpr int Kc  = Cc;         // 1024 reduce dim

DEVI unsigned short f2bf(float f) {            // RNE fp32 -> bf16
    unsigned u = __builtin_bit_cast(unsigned, f);
    u += 0x7FFFu + ((u >> 16) & 1u);
    return (unsigned short)(u >> 16);
}
DEVI float bf2f(unsigned short s) {
    unsigned u = ((unsigned)s) << 16;
    return __builtin_bit_cast(float, u);
}

typedef const __attribute__((address_space(1))) void* gbl_vp;
typedef __attribute__((address_space(3))) void* lds_vp;
DEVI void gload16(const unsigned short* g, unsigned short* l) {
    __builtin_amdgcn_global_load_lds((gbl_vp)g, (lds_vp)l, 16, 0, 0);
}

// ---------------------------------------------------------------------------
// Prep 0: RoPE table  tab[t][d] = (cos(t*theta_d), sin(t*theta_d)), d=0..31
// ---------------------------------------------------------------------------
__global__ void rope_tab_kernel(f32x2* __restrict__ tab)
{
    const int i = blockIdx.x * blockDim.x + threadIdx.x;   // 0 .. 2048*32
    const int t = i >> 5, d = i & 31;
    float theta = exp2f(-(float)d * 0.41524101186186f);    // 10000^(-d/32)
    float s, c;
    sincosf((float)t * theta, &s, &c);
    f32x2 v; v[0] = c; v[1] = s;
    tab[i] = v;
}

// ---------------------------------------------------------------------------
// Prep 1: fp32 -> bf16 elementwise (x). 8 elems/thread.
// ---------------------------------------------------------------------------
__global__ void cvt_kernel(const float* __restrict__ in,
                           unsigned short* __restrict__ out)
{
    const size_t i = ((size_t)blockIdx.x * blockDim.x + threadIdx.x) * 8;
    f32x4 a = *reinterpret_cast<const f32x4*>(in + i);
    f32x4 b = *reinterpret_cast<const f32x4*>(in + i + 4);
    u16x8 o;
    o[0] = f2bf(a[0]); o[1] = f2bf(a[1]); o[2] = f2bf(a[2]); o[3] = f2bf(a[3]);
    o[4] = f2bf(b[0]); o[5] = f2bf(b[1]); o[6] = f2bf(b[2]); o[7] = f2bf(b[3]);
    *reinterpret_cast<u16x8*>(out + i) = o;
}

// ---------------------------------------------------------------------------
// Prep 2: W [K][N] fp32 -> Wt [N][K] bf16 (transpose + convert), 64x64 tiles.
// ---------------------------------------------------------------------------
__global__ void wt_kernel(const float* __restrict__ W,
                          unsigned short* __restrict__ Wt, int N, int K)
{
    __shared__ unsigned short Ts[64][72];
    const int tid = threadIdx.x;
    const int n0 = blockIdx.x * 64, k0 = blockIdx.y * 64;

    #pragma unroll
    for (int i = 0; i < 4; ++i) {
        int kr = (tid >> 4) + i * 16, nc = (tid & 15) * 4;
        f32x4 v = *reinterpret_cast<const f32x4*>(W + (size_t)(k0 + kr) * N + n0 + nc);
        #pragma unroll
        for (int e = 0; e < 4; ++e) Ts[kr][nc + e] = f2bf(v[e]);
    }
    __syncthreads();
    #pragma unroll
    for (int i = 0; i < 2; ++i) {
        int s = tid * 2 + i;
        int n = s >> 3, k8 = (s & 7) * 8;
        u16x8 o;
        #pragma unroll
        for (int j = 0; j < 8; ++j) o[j] = Ts[k8 + j][n];
        *reinterpret_cast<u16x8*>(Wt + (size_t)(n0 + n) * K + k0 + k8) = o;
    }
}

// ---------------------------------------------------------------------------
// bf16 GEMM (R13 proven): C = A @ Bt^T + bias
// 128x128 tile, BK=64, 256 thr = 4 waves; global_load_lds w=16 staging,
// pre-swizzled source + XOR ds_read (0 conflicts), XCD m-slice L2 mapping.
// MODE 0: Q -> RoPE * softmax-scale (NEW: scale folded into Q);
//         K -> RoPE; V -> LDS-transposed coalesced 16B stores.
// MODE 1: fp32 + bias to f_out.
// ---------------------------------------------------------------------------
template <int MODE, int NCOLS>
__global__ void gemm_kernel(const unsigned short* __restrict__ A,
                            const unsigned short* __restrict__ Bt,
                            const float* __restrict__ bias,
                            const f32x2* __restrict__ rope_t,
                            unsigned short* __restrict__ q_out,
                            unsigned short* __restrict__ k_out,
                            unsigned short* __restrict__ v_out,
                            float* __restrict__ f_out)
{
    __shared__ unsigned short SM[2 * 128 * 64];   // As | Bs ; reused as Tv
    unsigned short* As = SM;
    unsigned short* Bs = SM + 128 * 64;

    const int tid  = threadIdx.x;
    const int lane = tid & 63, wid = tid >> 6;
    const int wr = wid >> 1, wc = wid & 1;
    const int lrow = lane & 15, lk = lane >> 4;

    // L2-locality mapping: xcd owns 8 m-tiles x all n-tiles.
    const int xcd = blockIdx.x & 7, loc = blockIdx.x >> 3;
    const int m0 = (xcd * 8 + (loc & 7)) * 128;
    const int n0 = (loc >> 3) * 128;

    f32x4 acc[4][4] = {};

    for (int kt = 0; kt < Kc / 64; ++kt) {
        const int k0 = kt * 64;
        #pragma unroll
        for (int i = 0; i < 4; ++i) {
            const int s   = ((i * 4 + wid) << 6) + lane;
            const int row = s >> 3;
            const int gc  = (s & 7) ^ (row & 7);
            gload16(A  + (size_t)(m0 + row) * Kc + k0 + gc * 8, &As[(i * 4 + wid) << 9]);
            gload16(Bt + (size_t)(n0 + row) * Kc + k0 + gc * 8, &Bs[(i * 4 + wid) << 9]);
        }
        __syncthreads();

        #pragma unroll
        for (int kk = 0; kk < 2; ++kk) {
            bf16x8 a[4], b[4];
            #pragma unroll
            for (int mt = 0; mt < 4; ++mt) {
                const int ra = wr * 64 + mt * 16 + lrow;
                a[mt] = __builtin_bit_cast(bf16x8,
                    *reinterpret_cast<const u16x8*>(&As[ra * 64 + (((kk * 4 + lk) ^ (ra & 7)) << 3)]));
            }
            #pragma unroll
            for (int nt = 0; nt < 4; ++nt) {
                const int rb = wc * 64 + nt * 16 + lrow;
                b[nt] = __builtin_bit_cast(bf16x8,
                    *reinterpret_cast<const u16x8*>(&Bs[rb * 64 + (((kk * 4 + lk) ^ (rb & 7)) << 3)]));
            }
            #pragma unroll
            for (int mt = 0; mt < 4; ++mt)
                #pragma unroll
                for (int nt = 0; nt < 4; ++nt)
                    acc[mt][nt] = __builtin_amdgcn_mfma_f32_16x16x32_bf16(a[mt], b[nt], acc[mt][nt], 0, 0, 0);
        }
        __syncthreads();
    }

    // ---- epilogue ----
    if constexpr (MODE == 1) {
        #pragma unroll
        for (int mt = 0; mt < 4; ++mt)
            #pragma unroll
            for (int nt = 0; nt < 4; ++nt)
                #pragma unroll
                for (int r = 0; r < 4; ++r) {
                    int grow = m0 + wr * 64 + mt * 16 + lk * 4 + r;
                    int gcol = n0 + wc * 64 + nt * 16 + lrow;
                    f_out[(size_t)grow * Cc + gcol] = acc[mt][nt][r] + bias[gcol];
                }
    } else if (n0 >= 2 * Cc) {
        // ---- V: transpose via LDS (stride 136, 16B-aligned rows), 2 passes
        unsigned short* Tv = SM;                  // 64 x 136 u16 = 17.4 KB
        const int bb = m0 >> 11, t0 = m0 & (Tc - 1);
        #pragma unroll
        for (int p = 0; p < 2; ++p) {
            if (wc == p) {
                #pragma unroll
                for (int mt = 0; mt < 4; ++mt)
                    #pragma unroll
                    for (int nt = 0; nt < 4; ++nt)
                        #pragma unroll
                        for (int r = 0; r < 4; ++r) {
                            int hs_l = nt * 16 + lrow;
                            int t_l  = wr * 64 + mt * 16 + lk * 4 + r;
                            int gcol = n0 + wc * 64 + nt * 16 + lrow;
                            Tv[hs_l * 136 + t_l] = f2bf(acc[mt][nt][r] + bias[gcol]);
                        }
            }
            __syncthreads();
            const int h  = ((n0 - 2 * Cc) >> 6) + p;     // head 0..15
            const int bh = bb * Hc + h;
            #pragma unroll
            for (int i = 0; i < 4; ++i) {
                int ch = i * 256 + tid;                  // 0..1023 chunks of 8
                int hs = ch >> 4, tc = ch & 15;
                u16x8 v = *reinterpret_cast<const u16x8*>(&Tv[hs * 136 + tc * 8]);
                *reinterpret_cast<u16x8*>(
                    &v_out[((size_t)bh * HSc + hs) * Tc + t0 + tc * 8]) = v;
            }
            __syncthreads();
        }
    } else {
        // ---- Q/K: fused table-RoPE scatter; Q additionally pre-scaled by
        // 0.125*log2(e) so attn's softmax skips the per-element multiply.
        const bool isQ = (n0 < Cc);
        unsigned short* dst = isQ ? q_out : k_out;
        const float oscale = isQ ? 0.18033688011112042f : 1.0f;
        #pragma unroll
        for (int mt = 0; mt < 4; ++mt)
            #pragma unroll
            for (int nt = 0; nt < 4; ++nt)
                #pragma unroll
                for (int r = 0; r < 4; ++r) {
                    int grow = m0 + wr * 64 + mt * 16 + lk * 4 + r;
                    int gcol = n0 + wc * 64 + nt * 16 + lrow;
                    float val = acc[mt][nt][r] + bias[gcol];
                    int cc   = gcol & (Cc - 1);
                    int h    = cc >> 6, hs = cc & 63;
                    int bb   = grow >> 11, t = grow & (Tc - 1);
                    int bh   = bb * Hc + h;
                    float partner = __shfl_xor(val, 1, 64);
                    const bool ev = !(lrow & 1);
                    float x1 = ev ? val : partner;
                    float x2 = ev ? partner : val;
                    int d = hs >> 1;
                    f32x2 cs = rope_t[t * 32 + d];
                    float o = ev ? (x1 * cs[0] - x2 * cs[1])
                                 : (x1 * cs[1] + x2 * cs[0]);
                    int hs_out = ev ? d : d + 32;
                    dst[((size_t)bh * Tc + t) * HSc + hs_out] = f2bf(o * oscale);
                }
    }
}

// ---------------------------------------------------------------------------
// Causal flash attention v8: v7 + VALU diet — Q arrives pre-scaled (no
// per-element multiply) and the causal mask runs only on diagonal tiles
// (wave-uniform branch; ~95% of tiles take the mask-free path).
// ---------------------------------------------------------------------------
__launch_bounds__(256, 3)
__global__ void attn_kernel(const unsigned short* __restrict__ Q,
                            const unsigned short* __restrict__ K,
                            const unsigned short* __restrict__ Vt,
                            unsigned short* __restrict__ O)
{
    constexpr int PST = 72;
    __shared__ unsigned short Ks[2][64 * 64];
    __shared__ unsigned short Vs[2][64 * 64];
    __shared__ unsigned short Pl[4 * 32 * PST];   // 32 P-rows per wave

    const int tid = threadIdx.x, lane = tid & 63, wid = tid >> 6;
    const int lrow = lane & 15, lk = lane >> 4;

    const int xcd = blockIdx.x & 7, loc = blockIdx.x >> 3;
    const int bh  = xcd * 8 + (loc & 7);
    const int qs  = 15 - (loc >> 3);
    const int b = bh >> 4, h = bh & 15;

    const unsigned short* Qb = Q  + (size_t)bh * Tc  * HSc;
    const unsigned short* Kb = K  + (size_t)bh * Tc  * HSc;
    const unsigned short* Vb = Vt + (size_t)bh * HSc * Tc;
    unsigned short* pl = &Pl[wid * 32 * PST];

    auto stage = [&](int buf, int kt) {
        const int kv0 = kt * 64;
        #pragma unroll
        for (int rr = 0; rr < 2; ++rr) {
            const int s   = ((rr * 4 + wid) << 6) + lane;
            const int row = s >> 3;
            const int gc  = (s & 7) ^ (row & 7);
            gload16(Kb + (size_t)(kv0 + row) * HSc + gc * 8, &Ks[buf][(rr * 4 + wid) << 9]);
            gload16(Vb + (size_t)row * Tc + kv0 + gc * 8,    &Vs[buf][(rr * 4 + wid) << 9]);
        }
    };

    const int wq0 = qs * 128 + wid * 32;
    const int ntile = 2 * qs + 2;

    bf16x8 qf[2][2];
    #pragma unroll
    for (int f = 0; f < 2; ++f)
        #pragma unroll
        for (int ks = 0; ks < 2; ++ks)
            qf[f][ks] = __builtin_bit_cast(bf16x8,
                *reinterpret_cast<const u16x8*>(Qb + (size_t)(wq0 + f * 16 + lrow) * HSc + ks * 32 + lk * 8));

    f32x4 Oacc[2][4] = {};
    float lsum[2][4] = {};

    stage(0, 0);
    for (int kt = 0; kt < ntile; ++kt) {
        const int kv0 = kt * 64;
        const int cur = kt & 1;
        const bool pre = (kt + 1 < ntile);
        if (pre) stage(cur ^ 1, kt + 1);
        if (pre) asm volatile("s_waitcnt vmcnt(4)" ::: "memory");
        else     asm volatile("s_waitcnt vmcnt(0)" ::: "memory");
        __builtin_amdgcn_s_barrier();

        if (kv0 <= wq0 + 31) {
            f32x4 S[2][4] = {};
            #pragma unroll
            for (int ct = 0; ct < 4; ++ct) {
                const int ro = ct * 16 + lrow;
                bf16x8 kf[2];
                #pragma unroll
                for (int ks = 0; ks < 2; ++ks)
                    kf[ks] = __builtin_bit_cast(bf16x8,
                        *reinterpret_cast<const u16x8*>(&Ks[cur][ro * 64 + (((ks * 4 + lk) ^ (ro & 7)) << 3)]));
                #pragma unroll
                for (int f = 0; f < 2; ++f)
                    #pragma unroll
                    for (int ks = 0; ks < 2; ++ks)
                        S[f][ct] = __builtin_amdgcn_mfma_f32_16x16x32_bf16(qf[f][ks], kf[ks], S[f][ct], 0, 0, 0);
            }

            // ---- P = exp2(S) (S pre-scaled); mask only on diagonal tiles
            #pragma unroll
            for (int f = 0; f < 2; ++f) {
                const bool mf = (kv0 + 63 > wq0 + f * 16);   // wave-uniform
                if (mf) {
                    #pragma unroll
                    for (int ct = 0; ct < 4; ++ct)
                        #pragma unroll
                        for (int r = 0; r < 4; ++r) {
                            float s = S[f][ct][r];
                            if (kv0 + ct * 16 + lrow > wq0 + f * 16 + lk * 4 + r) s = -1e30f;
                            float pv = __builtin_amdgcn_exp2f(s);
                            lsum[f][r] += pv;
                            pl[(f * 16 + lk * 4 + r) * PST + ct * 16 + lrow] =
                                __builtin_bit_cast(unsigned short, (__bf16)pv);
                        }
                } else {
                    #pragma unroll
                    for (int ct = 0; ct < 4; ++ct)
                        #pragma unroll
                        for (int r = 0; r < 4; ++r) {
                            float pv = __builtin_amdgcn_exp2f(S[f][ct][r]);
                            lsum[f][r] += pv;
                            pl[(f * 16 + lk * 4 + r) * PST + ct * 16 + lrow] =
                                __builtin_bit_cast(unsigned short, (__bf16)pv);
                        }
                }
            }
            asm volatile("s_waitcnt lgkmcnt(0)" ::: "memory");
            __builtin_amdgcn_sched_barrier(0);
            bf16x8 pf[2][2];
            #pragma unroll
            for (int f = 0; f < 2; ++f)
                #pragma unroll
                for (int ks = 0; ks < 2; ++ks)
                    pf[f][ks] = __builtin_bit_cast(bf16x8,
                        *reinterpret_cast<const u16x8*>(&pl[(f * 16 + lrow) * PST + ks * 32 + lk * 8]));

            #pragma unroll
            for (int nt = 0; nt < 4; ++nt) {
                const int ro = nt * 16 + lrow;
                bf16x8 vf[2];
                #pragma unroll
                for (int ks = 0; ks < 2; ++ks)
                    vf[ks] = __builtin_bit_cast(bf16x8,
                        *reinterpret_cast<const u16x8*>(&Vs[cur][ro * 64 + (((ks * 4 + lk) ^ (ro & 7)) << 3)]));
                #pragma unroll
                for (int f = 0; f < 2; ++f)
                    #pragma unroll
                    for (int ks = 0; ks < 2; ++ks)
                        Oacc[f][nt] = __builtin_amdgcn_mfma_f32_16x16x32_bf16(pf[f][ks], vf[ks], Oacc[f][nt], 0, 0, 0);
            }
        }
        asm volatile("s_waitcnt lgkmcnt(0)" ::: "memory");   // all LDS reads landed
        __builtin_amdgcn_sched_barrier(0);
        __builtin_amdgcn_s_barrier();         // safe to overwrite bufs
    }

    #pragma unroll
    for (int f = 0; f < 2; ++f) {
        #pragma unroll
        for (int mk = 1; mk < 16; mk <<= 1)
            #pragma unroll
            for (int r = 0; r < 4; ++r) lsum[f][r] += __shfl_xor(lsum[f][r], mk, 64);
        #pragma unroll
        for (int r = 0; r < 4; ++r) {
            float inv = 1.0f / lsum[f][r];
            int t = wq0 + f * 16 + lk * 4 + r;
            #pragma unroll
            for (int nt = 0; nt < 4; ++nt) {
                int col = h * 64 + nt * 16 + lrow;
                O[((size_t)b * Tc + t) * Cc + col] = f2bf(Oacc[f][nt][r] * inv);
            }
        }
    }
}

// ---------------------------------------------------------------------------
extern "C" void kernel_launch(void* const* d_in, const int* in_sizes, int n_in,
                              void* d_out, int out_size, void* d_ws, size_t ws_size,
                              hipStream_t stream)
{
    const float* x    = (const float*)d_in[0];
    const float* Wqkv = (const float*)d_in[1];
    const float* bqkv = (const float*)d_in[2];
    const float* Wo   = (const float*)d_in[3];
    const float* bo   = (const float*)d_in[4];
    float* out = (float*)d_out;

    char* ws = (char*)d_ws;
    size_t off = 0;
    auto alloc = [&](size_t bytes) {
        void* p = ws + off;
        off += (bytes + 255) & ~(size_t)255;
        return p;
    };
    const size_t elems = (size_t)Bc * Hc * Tc * HSc;          // 8.4M
    unsigned short* Qb  = (unsigned short*)alloc(elems * 2);
    unsigned short* Kb  = (unsigned short*)alloc(elems * 2);
    unsigned short* Vt  = (unsigned short*)alloc(elems * 2);
    unsigned short* Oa  = (unsigned short*)alloc(elems * 2);
    unsigned short* Xb  = (unsigned short*)alloc((size_t)Mc * Kc * 2);      // x bf16
    unsigned short* Wq_t = (unsigned short*)alloc((size_t)N1c * Kc * 2);    // Wqkv^T bf16
    unsigned short* Wo_t = (unsigned short*)alloc((size_t)Cc * Kc * 2);     // Wo^T bf16
    f32x2* Rt = (f32x2*)alloc((size_t)Tc * 32 * 8);                          // rope table

    rope_tab_kernel<<<(Tc * 32) / 256, 256, 0, stream>>>(Rt);
    cvt_kernel<<<(Mc * Kc) / (256 * 8), 256, 0, stream>>>(x, Xb);
    wt_kernel<<<dim3(N1c / 64, Kc / 64), 256, 0, stream>>>(Wqkv, Wq_t, N1c, Kc);
    wt_kernel<<<dim3(Cc / 64, Kc / 64), 256, 0, stream>>>(Wo, Wo_t, Cc, Kc);

    // 1) QKV projection + fused table-RoPE (Q pre-scaled) + coalesced-V scatter
    gemm_kernel<0, N1c><<<(N1c / 128) * (Mc / 128), 256, 0, stream>>>(
        Xb, Wq_t, bqkv, Rt, Qb, Kb, Vt, nullptr);
    // 2) causal flash attention (1024 blocks, XCD-local LPT)
    attn_kernel<<<1024, 256, 0, stream>>>(Qb, Kb, Vt, Oa);
    // 3) output projection -> fp32 d_out (grid 512)
    gemm_kernel<1, Cc><<<(Cc / 128) * (Mc / 128), 256, 0, stream>>>(
        Oa, Wo_t, bo, nullptr, nullptr, nullptr, nullptr, out);
}